// Round 9
// baseline (4774.150 us; speedup 1.0000x reference)
//
#include <hip/hip_runtime.h>

#define NS 8
#define ML 4096
#define HD 1024
#define K2 2048
#define NEV 32768
#define NLEV 12
#define NE 16384
#define NSLOT (NS * ML)
#define CAP 8
#define BK 64
#define NT (K2 / BK)          // 32 K-tiles
#define LDS_BYTES 98304       // 3 x 32KB A buffers (B lives in registers)

typedef __attribute__((ext_vector_type(8))) short bf16x8;
typedef __attribute__((ext_vector_type(4))) float f32x4;

typedef __attribute__((address_space(1))) const void cvoid_g;
typedef __attribute__((address_space(3))) void void_l;

static __device__ __forceinline__ void load_lds_16(const void* g, void* l) {
    __builtin_amdgcn_global_load_lds((cvoid_g*)g, (void_l*)l, 16, 0, 0);
}

static __device__ __forceinline__ unsigned short f2bf(float f) {
    unsigned u = __float_as_uint(f);
    unsigned r = (u + 0x7fffu + ((u >> 16) & 1u)) >> 16;
    return (unsigned short)r;
}

static __device__ __forceinline__ float fast_tanh(float x) {
    return 1.0f - 2.0f / (__expf(2.0f * x) + 1.0f);
}

// ---- W [2048][1024] f32 -> WbT [1024][2048] bf16 (transposed) ----
__global__ void wt_kernel(const float* __restrict__ W, unsigned short* __restrict__ WbT) {
    __shared__ unsigned short tile[64][65];
    const int t = threadIdx.x;
    const int k0 = blockIdx.x * 64;
    const int n0 = blockIdx.y * 64;
#pragma unroll
    for (int i = 0; i < 16; i++) {
        int idx = i * 256 + t;
        int r = idx >> 6, c = idx & 63;
        tile[r][c] = f2bf(W[(size_t)(k0 + r) * HD + n0 + c]);
    }
    __syncthreads();
#pragma unroll
    for (int i = 0; i < 16; i++) {
        int idx = i * 256 + t;
        int r = idx >> 6, c = idx & 63;
        WbT[(size_t)(n0 + r) * K2 + k0 + c] = tile[c][r];
    }
}

// ---- char dedupe pass 1 ----
__global__ void char_ticket(const int* __restrict__ cseq, const int* __restrict__ cpos,
                            int* __restrict__ counts, int* __restrict__ ticket,
                            int* __restrict__ evlist) {
    const int e = blockIdx.x * 256 + threadIdx.x;
    if (e >= NEV) return;
    const int slot = cseq[e] * ML + cpos[e];
    const int t = atomicAdd(&counts[slot], 1);
    ticket[e] = t;
    if (t < CAP) evlist[slot * CAP + t] = e;
}

// ---- char dedupe pass 2: plain store, zero-fills empty slots ----
__global__ void char_slot_sum(const int* __restrict__ counts, const int* __restrict__ evlist,
                              const int* __restrict__ cid, const float* __restrict__ emb,
                              float* __restrict__ h) {
    const int slot = blockIdx.x;
    const int t = threadIdx.x;
    int n = counts[slot];
    if (n > CAP) n = CAP;
    float4 acc = {0.f, 0.f, 0.f, 0.f};
    for (int i = 0; i < n; i++) {
        const int e = evlist[slot * CAP + i];
        const int id = cid[e];
        const float4 v = ((const float4*)(emb + (size_t)id * HD))[t];
        acc.x += v.x; acc.y += v.y; acc.z += v.z; acc.w += v.w;
    }
    ((float4*)(h + (size_t)slot * HD))[t] = acc;
}

// ---- char overflow fallback ----
__global__ void char_overflow(const int* __restrict__ cseq, const int* __restrict__ cpos,
                              const int* __restrict__ cid, const int* __restrict__ ticket,
                              const float* __restrict__ emb, float* __restrict__ h) {
    const int e0 = blockIdx.x * 128;
    const int t = threadIdx.x;
    for (int i = 0; i < 128; i++) {
        const int e = e0 + i;
        if (ticket[e] < CAP) continue;
        const int slot = cseq[e] * ML + cpos[e];
        const int id = cid[e];
        const float4 v = ((const float4*)(emb + (size_t)id * HD))[t];
        float* dst = h + (size_t)slot * HD + t * 4;
        atomicAdd(dst + 0, v.x);
        atomicAdd(dst + 1, v.y);
        atomicAdd(dst + 2, v.z);
        atomicAdd(dst + 3, v.w);
    }
}

// ---- group-event dup detection (all 12 levels at once; indices are static) ----
__global__ void grp_count(const int* __restrict__ iseq, const int* __restrict__ ipos,
                          int* __restrict__ gcounts) {
    const int idx = blockIdx.x * 256 + threadIdx.x;   // 12*16384
    if (idx >= NLEV * NE) return;
    const int lev = idx >> 14;
    atomicAdd(&gcounts[lev * NSLOT + iseq[idx] * ML + ipos[idx]], 1);
}

__global__ void grp_dup(const int* __restrict__ iseq, const int* __restrict__ ipos,
                        const int* __restrict__ gcounts, unsigned char* __restrict__ dup) {
    const int idx = blockIdx.x * 256 + threadIdx.x;
    if (idx >= NLEV * NE) return;
    const int lev = idx >> 14;
    dup[idx] = (gcounts[lev * NSLOT + iseq[idx] * ML + ipos[idx]] > 1) ? 1 : 0;
}

// ---- bf16 shadow of h: full init (after char phase) ----
__global__ void hbf_init(const float* __restrict__ h, unsigned short* __restrict__ hbf) {
    const size_t i = (size_t)blockIdx.x * 256 + threadIdx.x;   // over NSLOT*HD/4
    const float4 v = ((const float4*)h)[i];
    ushort4 p;
    p.x = f2bf(v.x); p.y = f2bf(v.y); p.z = f2bf(v.z); p.w = f2bf(v.w);
    ((ushort4*)hbf)[i] = p;
}

// ---- bf16 shadow: refresh rows touched by this level's scatter ----
// dup rows are written by multiple blocks with IDENTICAL data (benign).
__global__ void hbf_refresh(const float* __restrict__ h, const int* __restrict__ iseq,
                            const int* __restrict__ ipos, unsigned short* __restrict__ hbf) {
    const int e = blockIdx.x;
    const int t = threadIdx.x;
    const size_t row = (size_t)iseq[e] * ML + ipos[e];
    const float4 v = ((const float4*)(h + row * HD))[t];
    ushort4 p;
    p.x = f2bf(v.x); p.y = f2bf(v.y); p.z = f2bf(v.z); p.w = f2bf(v.w);
    ((ushort4*)(hbf + row * HD))[t] = p;
}

// ---- fused GEMM + bias + tanh + dedupe'd scatter ----
// 256x256 tile, BK=64, 8 waves (2M x 4N).
// Round-9: B IN REGISTERS (wave-private fragments straight from L2-resident WbT,
// double-buffered one tile ahead); A through TRIPLE-buffered LDS (3x32KB,
// prefetch distance 2 -> ~2-tile flight covers L3 latency). LDS traffic/tile
// drops 256KB -> 160KB (reads 128K + writes 32K ~ 1800cyc < MFMA 2483cyc), so
// the MFMA pipe is the sole longest resource. One vmcnt(4)+barrier per tile;
// per-thread VMEM queue invariant at the wait: [A(kt+1):4, B(kt+1):8, A(kt+2):4]
// -> vmcnt(4) retires exactly A(kt+1)+B(kt+1). bfP/bfQ ping-pong via unroll-2
// (static indexing, no scratch).
__global__ __launch_bounds__(512, 2) void gemm_scatter(
    const unsigned short* __restrict__ hbf,
    const unsigned short* __restrict__ WbT,
    const float* __restrict__ bias,
    const int* __restrict__ iseq, const int* __restrict__ ifirst,
    const int* __restrict__ isecond, const int* __restrict__ ipos,
    const unsigned char* __restrict__ dup,
    float* __restrict__ h) {
    extern __shared__ unsigned short lds[];
    const int t = threadIdx.x;
    const int lane = t & 63;
    const int w = t >> 6;            // 0..7
    const int wm = w >> 2;           // 0..1  (M half: 128 rows each)
    const int wn = (w & 3) * 64;     // 0,64,128,192 (N quarter: 64 cols)
    const int fr = lane & 15, fq = lane >> 4;

    // bijective XCD swizzle: 256 blocks, 8 XCDs; blocks on one XCD share a B-panel.
    const int bid = blockIdx.x;
    const int xcd = bid & 7, bix = bid >> 3;
    const int row0 = ((xcd & 1) * 32 + bix) * 256;   // 64 row blocks
    const int col0 = (xcd >> 1) * 256;               // 4 col blocks

    // A staging geometry: chunk c covers event rows c*64..c*64+63; thread t
    // handles row tr within chunk, 16B-position (t&7), xor-swizzled source sp.
    const int tr = t >> 3;
    const int sp = (t & 7) ^ (tr & 7);
    unsigned offA0[4], offA1[4];                     // elem offsets into hbf
#pragma unroll
    for (int c = 0; c < 4; c++) {
        const int e = row0 + tr + c * 64;
        const int seq = iseq[e];
        offA0[c] = (unsigned)((seq * ML + ifirst[e]) * HD + sp * 8);
        offA1[c] = (unsigned)((seq * ML + isecond[e]) * HD + sp * 8);
    }

    // B fragment offsets (elem) into WbT: row (col0+wn+nt*16+fr), k-slot (ks*4+fq)*8
    unsigned offB[2][4];
#pragma unroll
    for (int ks = 0; ks < 2; ks++)
#pragma unroll
        for (int nt = 0; nt < 4; nt++)
            offB[ks][nt] = (unsigned)((col0 + wn + nt * 16 + fr) * K2 + (ks * 4 + fq) * 8);

    f32x4 acc[8][4];
#pragma unroll
    for (int i = 0; i < 8; i++)
#pragma unroll
        for (int j = 0; j < 4; j++) acc[i][j] = (f32x4){0.f, 0.f, 0.f, 0.f};

    bf16x8 bfP[2][4], bfQ[2][4];

    // prologue: stage A(0)->buf0, load B(0)->bfP, stage A(1)->buf1
    // queue [A0:4, B0:8, A1:4] -> vmcnt(4) retires A0+B0, leaves A1 in flight.
    {
        unsigned short* d0 = lds;
        unsigned short* d1 = lds + 16384;
#pragma unroll
        for (int c = 0; c < 4; c++)
            load_lds_16(hbf + offA0[c], &d0[(c * 512 + t) * 8]);
#pragma unroll
        for (int ks = 0; ks < 2; ks++)
#pragma unroll
            for (int nt = 0; nt < 4; nt++)
                bfP[ks][nt] = *(const bf16x8*)(WbT + offB[ks][nt]);
#pragma unroll
        for (int c = 0; c < 4; c++)
            load_lds_16(hbf + offA0[c] + 64, &d1[(c * 512 + t) * 8]);
    }
    asm volatile("s_waitcnt vmcnt(4)\n\ts_barrier" ::: "memory");

    auto body = [&](int kt, bf16x8 (&bfC)[2][4], bf16x8 (&bfN)[2][4]) {
        const unsigned short* sA = lds + (kt % 3) * 16384;

        // A fragment reads (this tile) from LDS
        bf16x8 af0[2][4], af1[2][4];
#pragma unroll
        for (int ks = 0; ks < 2; ks++) {
            const int qs = ((ks * 4 + fq) ^ (fr & 7)) * 8;
#pragma unroll
            for (int mt = 0; mt < 4; mt++)
                af0[ks][mt] = *(const bf16x8*)&sA[(wm * 128 + mt * 16 + fr) * BK + qs];
#pragma unroll
            for (int mt = 0; mt < 4; mt++)
                af1[ks][mt] = *(const bf16x8*)&sA[(wm * 128 + 64 + mt * 16 + fr) * BK + qs];
        }

        // issue B(kt+1) -> registers (next buffer)
        if (kt + 1 < NT) {
            const unsigned kb = (unsigned)((kt + 1) * BK);
#pragma unroll
            for (int ks = 0; ks < 2; ks++)
#pragma unroll
                for (int nt = 0; nt < 4; nt++)
                    bfN[ks][nt] = *(const bf16x8*)(WbT + offB[ks][nt] + kb);
        }

        // issue A-stage (kt+2) -> buf[(kt+2)%3]
        if (kt + 2 < NT) {
            unsigned short* nA = lds + ((kt + 2) % 3) * 16384;
            const unsigned koA = (unsigned)(((kt + 2) * BK) & 1023);
            const int hsel = (kt + 2) >= (NT / 2);
#pragma unroll
            for (int c = 0; c < 4; c++) {
                const unsigned o = (hsel ? offA1[c] : offA0[c]) + koA;
                load_lds_16(hbf + o, &nA[(c * 512 + t) * 8]);
            }
        }

        __builtin_amdgcn_s_setprio(1);
#pragma unroll
        for (int ks = 0; ks < 2; ks++)
#pragma unroll
            for (int mt = 0; mt < 4; mt++)
#pragma unroll
                for (int nt = 0; nt < 4; nt++)
                    acc[mt][nt] = __builtin_amdgcn_mfma_f32_16x16x32_bf16(
                        af0[ks][mt], bfC[ks][nt], acc[mt][nt], 0, 0, 0);
#pragma unroll
        for (int ks = 0; ks < 2; ks++)
#pragma unroll
            for (int mt = 0; mt < 4; mt++)
#pragma unroll
                for (int nt = 0; nt < 4; nt++)
                    acc[4 + mt][nt] = __builtin_amdgcn_mfma_f32_16x16x32_bf16(
                        af1[ks][mt], bfC[ks][nt], acc[4 + mt][nt], 0, 0, 0);
        __builtin_amdgcn_s_setprio(0);

        if (kt + 1 < NT) {
            if (kt + 2 < NT) { asm volatile("s_waitcnt vmcnt(4)\n\ts_barrier" ::: "memory"); }
            else             { asm volatile("s_waitcnt vmcnt(0)\n\ts_barrier" ::: "memory"); }
        }
    };

    for (int kt = 0; kt < NT; kt += 2) {
        body(kt, bfP, bfQ);
        body(kt + 1, bfQ, bfP);
    }

    // epilogue: bias + tanh; sole-writer events use plain RMW, dups use atomics
    float bv[4];
#pragma unroll
    for (int ni = 0; ni < 4; ni++) bv[ni] = bias[col0 + wn + ni * 16 + fr];
#pragma unroll
    for (int mi = 0; mi < 8; mi++) {
#pragma unroll
        for (int r = 0; r < 4; r++) {
            const int e = row0 + wm * 128 + mi * 16 + fq * 4 + r;
            const int seq = iseq[e], pos = ipos[e];
            float* hrow = h + ((size_t)seq * ML + pos) * HD + col0 + wn;
            if (dup[e]) {
#pragma unroll
                for (int ni = 0; ni < 4; ni++) {
                    float x = fast_tanh(acc[mi][ni][r] + bv[ni]);
                    atomicAdd(&hrow[ni * 16 + fr], x);
                }
            } else {
#pragma unroll
                for (int ni = 0; ni < 4; ni++) {
                    float x = fast_tanh(acc[mi][ni][r] + bv[ni]);
                    hrow[ni * 16 + fr] += x;
                }
            }
        }
    }
}

// ---- final: h[:, 0, :] = 0 ----
__global__ void zero_first(float* __restrict__ h) {
    const int t = blockIdx.x * 256 + threadIdx.x;
    const int seq = t >> 10, d = t & 1023;
    h[(size_t)seq * ML * HD + d] = 0.0f;
}

extern "C" void kernel_launch(void* const* d_in, const int* in_sizes, int n_in,
                              void* d_out, int out_size, void* d_ws, size_t ws_size,
                              hipStream_t stream) {
    const int* char_i_seq = (const int*)d_in[0];
    const int* char_i_pos = (const int*)d_in[1];
    const int* char_ids   = (const int*)d_in[2];
    const int* grp_i_seq    = (const int*)d_in[3];
    const int* grp_i_first  = (const int*)d_in[4];
    const int* grp_i_second = (const int*)d_in[5];
    const int* grp_i_pos    = (const int*)d_in[6];
    const float* emb = (const float*)d_in[7];
    const float* W   = (const float*)d_in[8];
    const float* b   = (const float*)d_in[9];
    float* h = (float*)d_out;

    unsigned short* WbT = (unsigned short*)d_ws;                            // 4 MB @ 0
    unsigned short* hbf = (unsigned short*)((char*)d_ws + (8u << 20));      // 64 MB @ 8M
    int* counts = (int*)((char*)d_ws + (72u << 20));                        // 128 KB
    int* ticket = (int*)((char*)d_ws + (72u << 20) + (1u << 18));           // 128 KB
    int* evlist = (int*)((char*)d_ws + (72u << 20) + (1u << 19));           // 1 MB
    int* gcounts = (int*)((char*)d_ws + (74u << 20));                       // 1.5 MB
    unsigned char* gdup = (unsigned char*)((char*)d_ws + (76u << 20));      // 192 KB

    static bool attr_done = false;
    if (!attr_done) {
        (void)hipFuncSetAttribute((const void*)gemm_scatter,
                                  hipFuncAttributeMaxDynamicSharedMemorySize, LDS_BYTES);
        attr_done = true;
    }

    hipMemsetAsync(counts, 0, NSLOT * sizeof(int), stream);
    hipMemsetAsync(gcounts, 0, (size_t)NLEV * NSLOT * sizeof(int), stream);
    wt_kernel<<<dim3(32, 16), 256, 0, stream>>>(W, WbT);
    char_ticket<<<NEV / 256, 256, 0, stream>>>(char_i_seq, char_i_pos, counts, ticket, evlist);
    char_slot_sum<<<NSLOT, 256, 0, stream>>>(counts, evlist, char_ids, emb, h);
    char_overflow<<<NEV / 128, 256, 0, stream>>>(char_i_seq, char_i_pos, char_ids, ticket, emb, h);
    grp_count<<<(NLEV * NE) / 256, 256, 0, stream>>>(grp_i_seq, grp_i_pos, gcounts);
    grp_dup<<<(NLEV * NE) / 256, 256, 0, stream>>>(grp_i_seq, grp_i_pos, gcounts, gdup);
    hbf_init<<<NSLOT, 256, 0, stream>>>(h, hbf);   // NSLOT*HD/4 elems / 256 thr = NSLOT blocks

    for (int lev = 0; lev < NLEV; lev++) {
        const int* iseq = grp_i_seq + lev * NE;
        const int* ifir = grp_i_first + lev * NE;
        const int* isec = grp_i_second + lev * NE;
        const int* ipos = grp_i_pos + lev * NE;
        gemm_scatter<<<dim3(256), 512, LDS_BYTES, stream>>>(hbf, WbT, b, iseq, ifir, isec,
                                                            ipos, gdup + lev * NE, h);
        if (lev + 1 < NLEV)
            hbf_refresh<<<NE, 256, 0, stream>>>(h, iseq, ipos, hbf);
    }
    zero_first<<<32, 256, 0, stream>>>(h);
}